// Round 8
// baseline (138.988 us; speedup 1.0000x reference)
//
#include <hip/hip_runtime.h>

// STFT round-trip collapse:
//   conc == ft                      (mag/phase identity: mag*cos(atan2(i,r)) = r, etc.)
//   fwd composed with inv == diag(win)/SCALE   (pinv(fb)@fb = I; fb is 1026x1024 full column rank)
//   => out[b,u] = wav[b,u] * W1[u+PAD] / (EPS + W2[u+PAD])
// where W1/W2 sum win / win^2 over the <=4 frames overlapping padded sample t=u+PAD.
// Reflect padding only influences samples cropped by y[:, PAD:-PAD]. Pure streaming kernel.
//
// R4: 8-row runtime loop, kernel ~37us. R6: 1-row/thread + nt REGRESSED (82us).
// R7: 8-row unrolled burst: 42us, 2.4 TB/s, VALU 11%, occ 45% -> neither MLP nor
//     VALU limited; suspect one-shot flood/drain (8 blk/CU, no refill) vs ~40us floor.
// R8: 4 rows/thread, 4096 blocks (2 resident rounds/CU, halves interleaved on
//     blockIdx&1) to keep refill work during drain. Decisive A/B vs dispatch floor.

constexpr int kCols     = 2097152;       // T
constexpr int kRow4     = kCols / 4;     // float4 per row = 2^19
constexpr int kHop      = 256;
constexpr int kPad      = 512;           // FILTER_LENGTH/2
constexpr int kMaxFrame = 8192;          // nF - 1

typedef float fvec4 __attribute__((ext_vector_type(4)));

__global__ __launch_bounds__(256) void stft_roundtrip_kernel(
    const fvec4* __restrict__ wav,
    const float* __restrict__ sqw,       // square_window = win^2, 1024 floats
    fvec4* __restrict__ out)
{
    // Row-half interleaved on low blockIdx bit so both halves are in flight
    // throughout the kernel (smooth drain / refill overlap).
    const int half  = blockIdx.x & 1;                      // rows 0-3 or 4-7
    const int col4  = (blockIdx.x >> 1) * blockDim.x + threadIdx.x;
    if (col4 >= kRow4) return;
    const int u0 = col4 * 4;

    // Per-column gain = W1 / (EPS + W2), from the actual square_window input.
    // Computed twice per column (once per row-half) — VALU stays cheap.
    fvec4 g;
#pragma unroll
    for (int q = 0; q < 4; ++q) {
        const int t   = u0 + q + kPad;
        const int fhi = t >> 8;          // highest candidate frame index
        const int m   = t & 255;         // window offset phase
        float w1 = 0.0f, w2 = 0.0f;
#pragma unroll
        for (int j = 0; j < 4; ++j) {
            const int f = fhi - j;       // frame index; window pos k = m + 256*j in [0,1024)
            if (f >= 0 && f <= kMaxFrame) {
                const float s = sqw[m + kHop * j];
                w2 += s;
                w1 += sqrtf(s);          // win[k] >= 0 (Hann)
            }
        }
        g[q] = w1 / (1e-9f + w2);
    }

    // 4 rows per thread: independent load->mul->store chains, unrolled so the
    // compiler issues all loads early and retires stores with fine-grained vmcnt.
    const size_t base = (size_t)(half * 4) * kRow4 + (size_t)col4;
    fvec4 v[4];
#pragma unroll
    for (int b = 0; b < 4; ++b)
        v[b] = wav[base + (size_t)b * kRow4];
#pragma unroll
    for (int b = 0; b < 4; ++b)
        out[base + (size_t)b * kRow4] = v[b] * g;
}

extern "C" void kernel_launch(void* const* d_in, const int* in_sizes, int n_in,
                              void* d_out, int out_size, void* d_ws, size_t ws_size,
                              hipStream_t stream)
{
    const fvec4* wav = (const fvec4*)d_in[0];   // (8, 2097152) f32
    const float* sqw = (const float*)d_in[3];   // (1024,) f32
    fvec4* out = (fvec4*)d_out;                 // (8, 2097152) f32

    const int threads = 256;
    const int blocks  = 2 * ((kRow4 + threads - 1) / threads);   // 4096
    stft_roundtrip_kernel<<<blocks, threads, 0, stream>>>(wav, sqw, out);
}

// Round 9
// 132.709 us; speedup vs baseline: 1.0473x; 1.0473x over previous
//
#include <hip/hip_runtime.h>

// STFT round-trip collapse:
//   conc == ft                      (mag/phase identity: mag*cos(atan2(i,r)) = r, etc.)
//   fwd composed with inv == diag(win)/SCALE   (pinv(fb)@fb = I; fb is 1026x1024 full column rank)
//   => out[b,u] = wav[b,u] * W1[u+PAD] / (EPS + W2[u+PAD])
// Hann + hop=L/4: interior overlap sums are phase-independent (W1=2, W2=3/2 exactly;
// quarter-period cosine phases cancel), so the gain is a single constant except in
// the first/last 256 columns (3-frame coverage). Reflect padding is fully cropped.
//
// R4 ~37us / R7 42us / R8 48.5us: one-shot load-batch/store-batch shapes stall at
// ~3.2 TB/s combined. R9: m13-style flat GRID-STRIDE copy-scale loop (continuous
// per-wave issue), bulk gain = scalar constant, per-column math only on edge groups.

constexpr int kRow4   = 524288;          // float4 per row (2^19)
constexpr int kBatch  = 8;
constexpr int kTotal4 = kBatch * kRow4;  // 4,194,304
constexpr int kHop    = 256;
constexpr int kPad    = 512;             // FILTER_LENGTH/2
constexpr int kMaxFrame = 8192;          // nF - 1

typedef float fvec4 __attribute__((ext_vector_type(4)));

__global__ __launch_bounds__(256) void stft_roundtrip_kernel(
    const fvec4* __restrict__ wav,
    const float* __restrict__ sqw,       // square_window = win^2, 1024 floats
    fvec4* __restrict__ out)
{
    const int gid    = blockIdx.x * blockDim.x + threadIdx.x;
    const int stride = gridDim.x * blockDim.x;

    // Bulk (interior) gain, computed once per thread from phase 0 of sqw.
    // Analytically identical for every interior phase: W1=2, W2=1.5.
    float w1 = 0.0f, w2 = 0.0f;
#pragma unroll
    for (int j = 0; j < 4; ++j) {
        const float s = sqw[j * kHop];
        w2 += s;
        w1 += sqrtf(s);
    }
    const float c = w1 / (1e-9f + w2);

#pragma unroll 4
    for (int i = gid; i < kTotal4; i += stride) {
        const int col4 = i & (kRow4 - 1);          // float4 column group within row
        fvec4 g = {c, c, c, c};
        if (col4 < 64 || col4 >= kRow4 - 64) {     // first/last 256 columns: <4 frames
            const int u0 = col4 * 4;
#pragma unroll
            for (int q = 0; q < 4; ++q) {
                const int t   = u0 + q + kPad;
                const int fhi = t >> 8;
                const int m   = t & 255;
                float a = 0.0f, b = 0.0f;
#pragma unroll
                for (int j = 0; j < 4; ++j) {
                    const int f = fhi - j;         // window pos k = m + 256*j
                    if (f >= 0 && f <= kMaxFrame) {
                        const float s = sqw[m + kHop * j];
                        b += s;
                        a += sqrtf(s);
                    }
                }
                g[q] = a / (1e-9f + b);
            }
        }
        out[i] = wav[i] * g;
    }
}

extern "C" void kernel_launch(void* const* d_in, const int* in_sizes, int n_in,
                              void* d_out, int out_size, void* d_ws, size_t ws_size,
                              hipStream_t stream)
{
    const fvec4* wav = (const fvec4*)d_in[0];   // (8, 2097152) f32
    const float* sqw = (const float*)d_in[3];   // (1024,) f32
    fvec4* out = (fvec4*)d_out;                 // (8, 2097152) f32

    const int threads = 256;
    const int blocks  = 2048;                   // 8 blocks/CU; 8 grid-stride iters/thread
    stft_roundtrip_kernel<<<blocks, threads, 0, stream>>>(wav, sqw, out);
}